// Round 1
// baseline (58480.609 us; speedup 1.0000x reference)
//
#include <hip/hip_runtime.h>
#include <hip/hip_bf16.h>

__device__ __forceinline__ float fast_exp2(float x){
#if __has_builtin(__builtin_amdgcn_exp2f)
  return __builtin_amdgcn_exp2f(x);
#else
  return exp2f(x);
#endif
}
__device__ __forceinline__ float fast_rcp(float x){
#if __has_builtin(__builtin_amdgcn_rcpf)
  return __builtin_amdgcn_rcpf(x);
#else
  return 1.0f/x;
#endif
}

#define LOG2E 1.442695040888963f

// Lane->row mapping used by xproj and scan (must match):
// q in [0,256): w=q>>6, l=q&63, g=l>>4, u16=l&15 -> row = g*64 + w*16 + u16
// Gates of unit u = w*16+u16 live in lanes l, l^16, l^32, l^48 of wave w.

__global__ __launch_bounds__(256) void xproj_kernel(
    const float* __restrict__ x, const float* __restrict__ W_ih,
    const float* __restrict__ b_ih, const float* __restrict__ b_hh,
    float* __restrict__ xp, int T)
{
  const int tid = threadIdx.x;
  const int w = tid >> 6, l = tid & 63, g = l >> 4, u16 = l & 15;
  const int row = g*64 + w*16 + u16;
  float wv[64];
  {
    const float4* wr = (const float4*)(W_ih + (size_t)row*64);
    #pragma unroll
    for (int k=0;k<16;++k){ float4 q = wr[k]; wv[4*k]=q.x; wv[4*k+1]=q.y; wv[4*k+2]=q.z; wv[4*k+3]=q.w; }
  }
  const float bias = b_ih[row] + b_hh[row];
  __shared__ alignas(16) float xs[8][64];
  const int t0 = blockIdx.x * 128;
  for (int tt=0; tt<128; tt+=8){
    __syncthreads();
    xs[tid>>6][tid&63] = x[(size_t)(t0+tt)*64 + tid];
    const int f2 = tid + 256;
    xs[f2>>6][f2&63] = x[(size_t)(t0+tt)*64 + f2];
    __syncthreads();
    #pragma unroll
    for (int j=0;j<8;++j){
      const float4* xr = (const float4*)xs[j];
      float a0=0,a1=0,a2=0,a3=0;
      #pragma unroll
      for (int k=0;k<16;++k){
        float4 q = xr[k];
        a0 = fmaf(wv[4*k+0], q.x, a0);
        a1 = fmaf(wv[4*k+1], q.y, a1);
        a2 = fmaf(wv[4*k+2], q.z, a2);
        a3 = fmaf(wv[4*k+3], q.w, a3);
      }
      xp[(size_t)(t0+tt+j)*256 + tid] = bias + ((a0+a1)+(a2+a3));
    }
  }
}

// MODE 0: xp precomputed (fast path). MODE 1: x-proj fused (ws holds hs only).
// MODE 2: everything fused incl. output dense (zero ws).
template<int MODE>
__global__ __launch_bounds__(256,1) void lstm_scan(
    const float* __restrict__ xp, const float* __restrict__ x,
    const float* __restrict__ W_ih, const float* __restrict__ W_hh,
    const float* __restrict__ b_ih, const float* __restrict__ b_hh,
    const float* __restrict__ W_lin, const float* __restrict__ b_lin,
    const float* __restrict__ W_fin, const float* __restrict__ b_fin,
    float* __restrict__ hs, float* __restrict__ out, int T)
{
  const int tid = threadIdx.x;
  const int w = tid >> 6, l = tid & 63, g = l >> 4, u16 = l & 15;
  const int row = g*64 + w*16 + u16;
  const int u64i = w*16 + u16;

  float wv[64];
  { const float4* wr = (const float4*)(W_hh + (size_t)row*64);
    #pragma unroll
    for (int k=0;k<16;++k){ float4 q=wr[k]; wv[4*k]=q.x; wv[4*k+1]=q.y; wv[4*k+2]=q.z; wv[4*k+3]=q.w; } }

  const bool isg = (g == 2);
  const float kscale = isg ? (-2.f*LOG2E) : (-LOG2E);
  const float kmul = isg ? 2.f : 1.f;
  const float kadd = isg ? -1.f : 0.f;
  float c = 0.f;

  __shared__ alignas(16) float hbufs[2][64];
  if (tid < 64){ hbufs[0][tid] = 0.f; hbufs[1][tid] = 0.f; }

  float cur[8], nxt[8];
  const float* xq = nullptr;
  float wih[64]; float bias = 0.f;
  __shared__ alignas(16) float xlds[2][512];
  float px0=0.f, px1=0.f;
  const size_t N = (size_t)T * 64;

  if (MODE == 0){
    xq = xp + tid;
    #pragma unroll
    for (int j=0;j<8;++j) cur[j] = xq[(size_t)j*256];
  } else {
    const float4* wr = (const float4*)(W_ih + (size_t)row*64);
    #pragma unroll
    for (int k=0;k<16;++k){ float4 q=wr[k]; wih[4*k]=q.x; wih[4*k+1]=q.y; wih[4*k+2]=q.z; wih[4*k+3]=q.w; }
    bias = b_ih[row] + b_hh[row];
    px0 = x[tid]; px1 = x[(size_t)tid + 256];
    xlds[0][tid] = px0; xlds[0][tid+256] = px1;
    size_t i0 = (size_t)512 + tid, i1 = (size_t)512 + tid + 256;
    px0 = x[i0 < N ? i0 : (N-1)];
    px1 = x[i1 < N ? i1 : (N-1)];
  }

  float wlin[64], blin_l=0.f, wfin_l=0.f, bfin=0.f;
  if (MODE == 2){
    const float4* wr = (const float4*)(W_lin + (size_t)l*64);
    #pragma unroll
    for (int k=0;k<16;++k){ float4 q=wr[k]; wlin[4*k]=q.x; wlin[4*k+1]=q.y; wlin[4*k+2]=q.z; wlin[4*k+3]=q.w; }
    blin_l = b_lin[l]; wfin_l = W_fin[l]; bfin = b_fin[0];
  }

  __syncthreads();

  for (int tb = 0; tb < T; tb += 8){
    if (MODE == 0){
      if (tb + 8 < T){
        #pragma unroll
        for (int j=0;j<8;++j) nxt[j] = xq[(size_t)(tb+8+j)*256];
      }
    } else {
      const int gi = tb >> 3;
      float* xd = xlds[(gi+1)&1];
      xd[tid] = px0; xd[tid+256] = px1;
      const size_t base = (size_t)(gi+2) * 512;
      size_t i0 = base + tid, i1 = base + tid + 256;
      px0 = x[i0 < N ? i0 : (N-1)];
      px1 = x[i1 < N ? i1 : (N-1)];
    }
    #pragma unroll
    for (int j=0;j<8;++j){
      const int t = tb + j;
      const float4* hb = (const float4*)hbufs[t&1];
      float a0=0,a1=0,a2=0,a3=0;
      float m0=0,m1=0,m2=0,m3=0;
      #pragma unroll
      for (int k=0;k<16;++k){
        float4 hk = hb[k];
        a0 = fmaf(wv[4*k+0], hk.x, a0);
        a1 = fmaf(wv[4*k+1], hk.y, a1);
        a2 = fmaf(wv[4*k+2], hk.z, a2);
        a3 = fmaf(wv[4*k+3], hk.w, a3);
        if (MODE == 2){
          m0 = fmaf(wlin[4*k+0], fmaxf(hk.x,0.f), m0);
          m1 = fmaf(wlin[4*k+1], fmaxf(hk.y,0.f), m1);
          m2 = fmaf(wlin[4*k+2], fmaxf(hk.z,0.f), m2);
          m3 = fmaf(wlin[4*k+3], fmaxf(hk.w,0.f), m3);
        }
      }
      float z = (a0+a1)+(a2+a3);
      if (MODE == 0){
        z += cur[j];
      } else {
        const float4* xr = (const float4*)&xlds[(tb>>3)&1][j*64];
        float b0=0,b1=0,b2=0,b3=0;
        #pragma unroll
        for (int k=0;k<16;++k){
          float4 q = xr[k];
          b0 = fmaf(wih[4*k+0], q.x, b0);
          b1 = fmaf(wih[4*k+1], q.y, b1);
          b2 = fmaf(wih[4*k+2], q.z, b2);
          b3 = fmaf(wih[4*k+3], q.w, b3);
        }
        z += bias + ((b0+b1)+(b2+b3));
      }
      if (MODE == 2){
        float mid = fmaxf(blin_l + ((m0+m1)+(m2+m3)), 0.f);
        float po = wfin_l * mid;
        if (w == 0){
          po += __shfl_xor(po,1); po += __shfl_xor(po,2); po += __shfl_xor(po,4);
          po += __shfl_xor(po,8); po += __shfl_xor(po,16); po += __shfl_xor(po,32);
          if (l == 0 && t > 0) out[t-1] = po + bfin;
        }
      }
      float e = fast_exp2(z * kscale);
      float sgm = fast_rcp(1.f + e);
      float v = fmaf(sgm, kmul, kadd);
      const float s1 = __shfl_xor(v, 16);
      const float s2 = __shfl_xor(v, 32);
      const float s3 = __shfl_xor(v, 48);
      c = fmaf(s1, c, v * s2);
      const float e2 = fast_exp2((-2.f*LOG2E) * c);
      const float tc = fmaf(fast_rcp(1.f + e2), 2.f, -1.f);
      const float h = s3 * tc;
      if (l < 16){
        hbufs[(t&1)^1][u64i] = h;
        if (MODE <= 1) hs[(size_t)t*64 + u64i] = h;
      }
      __syncthreads();
    }
    if (MODE == 0){
      #pragma unroll
      for (int j=0;j<8;++j) cur[j] = nxt[j];
    }
  }
  if (MODE == 2){
    const float4* hb = (const float4*)hbufs[T&1];
    float m0=0,m1=0,m2=0,m3=0;
    #pragma unroll
    for (int k=0;k<16;++k){
      float4 hk = hb[k];
      m0 = fmaf(wlin[4*k+0], fmaxf(hk.x,0.f), m0);
      m1 = fmaf(wlin[4*k+1], fmaxf(hk.y,0.f), m1);
      m2 = fmaf(wlin[4*k+2], fmaxf(hk.z,0.f), m2);
      m3 = fmaf(wlin[4*k+3], fmaxf(hk.w,0.f), m3);
    }
    float mid = fmaxf(blin_l + ((m0+m1)+(m2+m3)), 0.f);
    float po = wfin_l * mid;
    if (w == 0){
      po += __shfl_xor(po,1); po += __shfl_xor(po,2); po += __shfl_xor(po,4);
      po += __shfl_xor(po,8); po += __shfl_xor(po,16); po += __shfl_xor(po,32);
      if (l == 0) out[T-1] = po + bfin;
    }
  }
}

__global__ __launch_bounds__(128) void postproc_kernel(
    const float* __restrict__ hs, const float* __restrict__ W_lin,
    const float* __restrict__ b_lin, const float* __restrict__ W_fin,
    const float* __restrict__ b_fin, float* __restrict__ out, int T)
{
  __shared__ alignas(16) float wl[4096];
  __shared__ float ht[128][65];
  __shared__ float sb[64], sw[64];
  const int tid = threadIdx.x;
  #pragma unroll
  for (int i=0;i<32;++i){ int f = tid + i*128; wl[f] = W_lin[f]; }
  if (tid < 64){ sb[tid] = b_lin[tid]; sw[tid] = W_fin[tid]; }
  const size_t t0 = (size_t)blockIdx.x * 128;
  #pragma unroll
  for (int i=0;i<64;++i){ int f = tid + i*128; ht[f>>6][f&63] = hs[t0*64 + f]; }
  __syncthreads();
  float rh[64];
  #pragma unroll
  for (int k=0;k<64;++k) rh[k] = fmaxf(ht[tid][k], 0.f);
  float acc = b_fin[0];
  for (int j=0;j<64;++j){
    const float4* wr = (const float4*)(wl + j*64);
    float m0=sb[j],m1=0,m2=0,m3=0;
    #pragma unroll
    for (int k=0;k<16;++k){
      float4 q = wr[k];
      m0 = fmaf(q.x, rh[4*k+0], m0);
      m1 = fmaf(q.y, rh[4*k+1], m1);
      m2 = fmaf(q.z, rh[4*k+2], m2);
      m3 = fmaf(q.w, rh[4*k+3], m3);
    }
    acc = fmaf(sw[j], fmaxf((m0+m1)+(m2+m3), 0.f), acc);
  }
  out[t0 + tid] = acc;
}

extern "C" void kernel_launch(void* const* d_in, const int* in_sizes, int n_in,
                              void* d_out, int out_size, void* d_ws, size_t ws_size,
                              hipStream_t stream)
{
  const float* x    = (const float*)d_in[0];
  const float* W_ih = (const float*)d_in[1];
  const float* W_hh = (const float*)d_in[2];
  const float* b_ih = (const float*)d_in[3];
  const float* b_hh = (const float*)d_in[4];
  const float* W_lin= (const float*)d_in[5];
  const float* b_lin= (const float*)d_in[6];
  const float* W_fin= (const float*)d_in[7];
  const float* b_fin= (const float*)d_in[8];
  float* out = (float*)d_out;
  const int T = in_sizes[0] / 64;
  const size_t xp_bytes = (size_t)T * 256 * sizeof(float);
  const size_t hs_bytes = (size_t)T * 64 * sizeof(float);

  if (ws_size >= xp_bytes + hs_bytes){
    float* xp = (float*)d_ws;
    float* hs = (float*)((char*)d_ws + xp_bytes);
    xproj_kernel<<<T/128, 256, 0, stream>>>(x, W_ih, b_ih, b_hh, xp, T);
    lstm_scan<0><<<1, 256, 0, stream>>>(xp, x, W_ih, W_hh, b_ih, b_hh,
                                        W_lin, b_lin, W_fin, b_fin, hs, out, T);
    postproc_kernel<<<T/128, 128, 0, stream>>>(hs, W_lin, b_lin, W_fin, b_fin, out, T);
  } else if (ws_size >= hs_bytes){
    float* hs = (float*)d_ws;
    lstm_scan<1><<<1, 256, 0, stream>>>(nullptr, x, W_ih, W_hh, b_ih, b_hh,
                                        W_lin, b_lin, W_fin, b_fin, hs, out, T);
    postproc_kernel<<<T/128, 128, 0, stream>>>(hs, W_lin, b_lin, W_fin, b_fin, out, T);
  } else {
    lstm_scan<2><<<1, 256, 0, stream>>>(nullptr, x, W_ih, W_hh, b_ih, b_hh,
                                        W_lin, b_lin, W_fin, b_fin, nullptr, out, T);
  }
}

// Round 2
// 51330.310 us; speedup vs baseline: 1.1393x; 1.1393x over previous
//
#include <hip/hip_runtime.h>
#include <hip/hip_bf16.h>

__device__ __forceinline__ float fast_exp2(float x){
#if __has_builtin(__builtin_amdgcn_exp2f)
  return __builtin_amdgcn_exp2f(x);
#else
  return exp2f(x);
#endif
}
__device__ __forceinline__ float fast_rcp(float x){
#if __has_builtin(__builtin_amdgcn_rcpf)
  return __builtin_amdgcn_rcpf(x);
#else
  return 1.0f/x;
#endif
}

// quad_perm DPP: xor1=0xB1 [1,0,3,2], xor2=0x4E [2,3,0,1], xor3=0x1B [3,2,1,0]
template<int CTRL>
__device__ __forceinline__ float qperm(float v){
  return __int_as_float(__builtin_amdgcn_update_dpp(0, __float_as_int(v), CTRL, 0xF, 0xF, true));
}

// LDS-only barrier: do NOT drain vmcnt (prefetch loads / hs stores stay in flight).
#define LDS_BARRIER() __asm__ __volatile__("s_waitcnt lgkmcnt(0)\n\ts_barrier" ::: "memory")

#define LOG2E 1.442695040888963f

// Lane->row mapping used by xproj and scan (must match):
// tid in [0,256): w=tid>>6, l=tid&63, gate=l&3, usub=l>>2 -> unit u=w*16+usub,
// row = gate*64 + u.  Gates of a unit live in one QUAD (lanes l^1,l^2,l^3).

__global__ __launch_bounds__(256) void xproj_kernel(
    const float* __restrict__ x, const float* __restrict__ W_ih,
    const float* __restrict__ b_ih, const float* __restrict__ b_hh,
    float* __restrict__ xp, int T)
{
  const int tid = threadIdx.x;
  const int w = tid >> 6, l = tid & 63;
  const int row = (l & 3) * 64 + w * 16 + (l >> 2);
  float wv[64];
  {
    const float4* wr = (const float4*)(W_ih + (size_t)row*64);
    #pragma unroll
    for (int k=0;k<16;++k){ float4 q = wr[k]; wv[4*k]=q.x; wv[4*k+1]=q.y; wv[4*k+2]=q.z; wv[4*k+3]=q.w; }
  }
  const float bias = b_ih[row] + b_hh[row];
  __shared__ alignas(16) float xs[8][64];
  const int t0 = blockIdx.x * 128;
  for (int tt=0; tt<128; tt+=8){
    __syncthreads();
    xs[tid>>6][tid&63] = x[(size_t)(t0+tt)*64 + tid];
    const int f2 = tid + 256;
    xs[f2>>6][f2&63] = x[(size_t)(t0+tt)*64 + f2];
    __syncthreads();
    #pragma unroll
    for (int j=0;j<8;++j){
      const float4* xr = (const float4*)xs[j];
      float a0=0,a1=0,a2=0,a3=0;
      #pragma unroll
      for (int k=0;k<16;++k){
        float4 q = xr[k];
        a0 = fmaf(wv[4*k+0], q.x, a0);
        a1 = fmaf(wv[4*k+1], q.y, a1);
        a2 = fmaf(wv[4*k+2], q.z, a2);
        a3 = fmaf(wv[4*k+3], q.w, a3);
      }
      xp[(size_t)(t0+tt+j)*256 + tid] = bias + ((a0+a1)+(a2+a3));
    }
  }
}

// MODE 0: xp precomputed (fast path). MODE 1: x-proj fused (ws holds hs only).
// MODE 2: everything fused incl. output dense (zero ws).
template<int MODE>
__global__ __launch_bounds__(256,1) void lstm_scan(
    const float* __restrict__ xp, const float* __restrict__ x,
    const float* __restrict__ W_ih, const float* __restrict__ W_hh,
    const float* __restrict__ b_ih, const float* __restrict__ b_hh,
    const float* __restrict__ W_lin, const float* __restrict__ b_lin,
    const float* __restrict__ W_fin, const float* __restrict__ b_fin,
    float* __restrict__ hs, float* __restrict__ out, int T)
{
  const int tid = threadIdx.x;
  const int w = tid >> 6, l = tid & 63;
  const int gate = l & 3;
  const int u64i = w * 16 + (l >> 2);      // unit index this lane's row belongs to
  const int row = gate * 64 + u64i;

  float wv[64];
  { const float4* wr = (const float4*)(W_hh + (size_t)row*64);
    #pragma unroll
    for (int k=0;k<16;++k){ float4 q=wr[k]; wv[4*k]=q.x; wv[4*k+1]=q.y; wv[4*k+2]=q.z; wv[4*k+3]=q.w; } }

  const bool isg = (gate == 2);
  const float kscale = isg ? (-2.f*LOG2E) : (-LOG2E);
  const float kmul = isg ? 2.f : 1.f;
  const float kadd = isg ? -1.f : 0.f;
  float c = 0.f;

  __shared__ alignas(16) float hbufs[2][64];
  if (tid < 64){ hbufs[0][tid] = 0.f; hbufs[1][tid] = 0.f; }

  float cur[8], nxt[8];
  const float* xq = nullptr;
  float wih[64]; float bias = 0.f;
  __shared__ alignas(16) float xlds[2][512];
  float px0=0.f, px1=0.f;
  const size_t N = (size_t)T * 64;

  if (MODE == 0){
    xq = xp + tid;
    #pragma unroll
    for (int j=0;j<8;++j) cur[j] = xq[(size_t)j*256];
  } else {
    const float4* wr = (const float4*)(W_ih + (size_t)row*64);
    #pragma unroll
    for (int k=0;k<16;++k){ float4 q=wr[k]; wih[4*k]=q.x; wih[4*k+1]=q.y; wih[4*k+2]=q.z; wih[4*k+3]=q.w; }
    bias = b_ih[row] + b_hh[row];
    px0 = x[tid]; px1 = x[(size_t)tid + 256];
    xlds[0][tid] = px0; xlds[0][tid+256] = px1;
    size_t i0 = (size_t)512 + tid, i1 = (size_t)512 + tid + 256;
    px0 = x[i0 < N ? i0 : (N-1)];
    px1 = x[i1 < N ? i1 : (N-1)];
  }

  float wlin[64], blin_l=0.f, wfin_l=0.f, bfin=0.f;
  if (MODE == 2){
    const float4* wr = (const float4*)(W_lin + (size_t)l*64);
    #pragma unroll
    for (int k=0;k<16;++k){ float4 q=wr[k]; wlin[4*k]=q.x; wlin[4*k+1]=q.y; wlin[4*k+2]=q.z; wlin[4*k+3]=q.w; }
    blin_l = b_lin[l]; wfin_l = W_fin[l]; bfin = b_fin[0];
  }

  __syncthreads();

  for (int tb = 0; tb < T; tb += 8){
    if (MODE == 0){
      if (tb + 8 < T){
        #pragma unroll
        for (int j=0;j<8;++j) nxt[j] = xq[(size_t)(tb+8+j)*256];
      }
    } else {
      const int gi = tb >> 3;
      float* xd = xlds[(gi+1)&1];
      xd[tid] = px0; xd[tid+256] = px1;
      const size_t base = (size_t)(gi+2) * 512;
      size_t i0 = base + tid, i1 = base + tid + 256;
      px0 = x[i0 < N ? i0 : (N-1)];
      px1 = x[i1 < N ? i1 : (N-1)];
    }
    #pragma unroll
    for (int j=0;j<8;++j){
      const int t = tb + j;
      const float4* hb = (const float4*)hbufs[t&1];
      float a0=0,a1=0,a2=0,a3=0;
      float m0=0,m1=0,m2=0,m3=0;
      #pragma unroll
      for (int k=0;k<16;++k){
        float4 hk = hb[k];
        a0 = fmaf(wv[4*k+0], hk.x, a0);
        a1 = fmaf(wv[4*k+1], hk.y, a1);
        a2 = fmaf(wv[4*k+2], hk.z, a2);
        a3 = fmaf(wv[4*k+3], hk.w, a3);
        if (MODE == 2){
          m0 = fmaf(wlin[4*k+0], fmaxf(hk.x,0.f), m0);
          m1 = fmaf(wlin[4*k+1], fmaxf(hk.y,0.f), m1);
          m2 = fmaf(wlin[4*k+2], fmaxf(hk.z,0.f), m2);
          m3 = fmaf(wlin[4*k+3], fmaxf(hk.w,0.f), m3);
        }
      }
      float z = (a0+a1)+(a2+a3);
      if (MODE == 0){
        z += cur[j];
      } else {
        const float4* xr = (const float4*)&xlds[(tb>>3)&1][j*64];
        float b0=0,b1=0,b2=0,b3=0;
        #pragma unroll
        for (int k=0;k<16;++k){
          float4 q = xr[k];
          b0 = fmaf(wih[4*k+0], q.x, b0);
          b1 = fmaf(wih[4*k+1], q.y, b1);
          b2 = fmaf(wih[4*k+2], q.z, b2);
          b3 = fmaf(wih[4*k+3], q.w, b3);
        }
        z += bias + ((b0+b1)+(b2+b3));
      }
      if (MODE == 2){
        float mid = fmaxf(blin_l + ((m0+m1)+(m2+m3)), 0.f);
        float po = wfin_l * mid;
        if (w == 0){
          po += __shfl_xor(po,1); po += __shfl_xor(po,2); po += __shfl_xor(po,4);
          po += __shfl_xor(po,8); po += __shfl_xor(po,16); po += __shfl_xor(po,32);
          if (l == 0 && t > 0) out[t-1] = po + bfin;
        }
      }
      float e = fast_exp2(z * kscale);
      float sgm = fast_rcp(1.f + e);
      float v = fmaf(sgm, kmul, kadd);
      // quad gate exchange (i,f,g,o live in lanes l^1,l^2,l^3 of this quad)
      const float q1 = qperm<0xB1>(v);   // xor 1
      const float q2 = qperm<0x4E>(v);   // xor 2
      const float q3 = qperm<0x1B>(v);   // xor 3
      // valid for gate==0 lanes: v=i, q1=f, q2=g, q3=o
      c = fmaf(q1, c, v * q2);
      const float e2 = fast_exp2((-2.f*LOG2E) * c);
      const float tc = fmaf(fast_rcp(1.f + e2), 2.f, -1.f);
      const float h = q3 * tc;
      if ((l & 3) == 0){
        hbufs[(t&1)^1][u64i] = h;
        if (MODE <= 1) hs[(size_t)t*64 + u64i] = h;
      }
      LDS_BARRIER();
    }
    if (MODE == 0){
      #pragma unroll
      for (int j=0;j<8;++j) cur[j] = nxt[j];
    }
  }
  if (MODE == 2){
    const float4* hb = (const float4*)hbufs[T&1];
    float m0=0,m1=0,m2=0,m3=0;
    #pragma unroll
    for (int k=0;k<16;++k){
      float4 hk = hb[k];
      m0 = fmaf(wlin[4*k+0], fmaxf(hk.x,0.f), m0);
      m1 = fmaf(wlin[4*k+1], fmaxf(hk.y,0.f), m1);
      m2 = fmaf(wlin[4*k+2], fmaxf(hk.z,0.f), m2);
      m3 = fmaf(wlin[4*k+3], fmaxf(hk.w,0.f), m3);
    }
    float mid = fmaxf(blin_l + ((m0+m1)+(m2+m3)), 0.f);
    float po = wfin_l * mid;
    if (w == 0){
      po += __shfl_xor(po,1); po += __shfl_xor(po,2); po += __shfl_xor(po,4);
      po += __shfl_xor(po,8); po += __shfl_xor(po,16); po += __shfl_xor(po,32);
      if (l == 0) out[T-1] = po + bfin;
    }
  }
}

__global__ __launch_bounds__(128) void postproc_kernel(
    const float* __restrict__ hs, const float* __restrict__ W_lin,
    const float* __restrict__ b_lin, const float* __restrict__ W_fin,
    const float* __restrict__ b_fin, float* __restrict__ out, int T)
{
  __shared__ alignas(16) float wl[4096];
  __shared__ float ht[128][65];
  __shared__ float sb[64], sw[64];
  const int tid = threadIdx.x;
  #pragma unroll
  for (int i=0;i<32;++i){ int f = tid + i*128; wl[f] = W_lin[f]; }
  if (tid < 64){ sb[tid] = b_lin[tid]; sw[tid] = W_fin[tid]; }
  const size_t t0 = (size_t)blockIdx.x * 128;
  #pragma unroll
  for (int i=0;i<64;++i){ int f = tid + i*128; ht[f>>6][f&63] = hs[t0*64 + f]; }
  __syncthreads();
  float rh[64];
  #pragma unroll
  for (int k=0;k<64;++k) rh[k] = fmaxf(ht[tid][k], 0.f);
  float acc = b_fin[0];
  for (int j=0;j<64;++j){
    const float4* wr = (const float4*)(wl + j*64);
    float m0=sb[j],m1=0,m2=0,m3=0;
    #pragma unroll
    for (int k=0;k<16;++k){
      float4 q = wr[k];
      m0 = fmaf(q.x, rh[4*k+0], m0);
      m1 = fmaf(q.y, rh[4*k+1], m1);
      m2 = fmaf(q.z, rh[4*k+2], m2);
      m3 = fmaf(q.w, rh[4*k+3], m3);
    }
    acc = fmaf(sw[j], fmaxf((m0+m1)+(m2+m3), 0.f), acc);
  }
  out[t0 + tid] = acc;
}

extern "C" void kernel_launch(void* const* d_in, const int* in_sizes, int n_in,
                              void* d_out, int out_size, void* d_ws, size_t ws_size,
                              hipStream_t stream)
{
  const float* x    = (const float*)d_in[0];
  const float* W_ih = (const float*)d_in[1];
  const float* W_hh = (const float*)d_in[2];
  const float* b_ih = (const float*)d_in[3];
  const float* b_hh = (const float*)d_in[4];
  const float* W_lin= (const float*)d_in[5];
  const float* b_lin= (const float*)d_in[6];
  const float* W_fin= (const float*)d_in[7];
  const float* b_fin= (const float*)d_in[8];
  float* out = (float*)d_out;
  const int T = in_sizes[0] / 64;
  const size_t xp_bytes = (size_t)T * 256 * sizeof(float);
  const size_t hs_bytes = (size_t)T * 64 * sizeof(float);

  if (ws_size >= xp_bytes + hs_bytes){
    float* xp = (float*)d_ws;
    float* hs = (float*)((char*)d_ws + xp_bytes);
    xproj_kernel<<<T/128, 256, 0, stream>>>(x, W_ih, b_ih, b_hh, xp, T);
    lstm_scan<0><<<1, 256, 0, stream>>>(xp, x, W_ih, W_hh, b_ih, b_hh,
                                        W_lin, b_lin, W_fin, b_fin, hs, out, T);
    postproc_kernel<<<T/128, 128, 0, stream>>>(hs, W_lin, b_lin, W_fin, b_fin, out, T);
  } else if (ws_size >= hs_bytes){
    float* hs = (float*)d_ws;
    lstm_scan<1><<<1, 256, 0, stream>>>(nullptr, x, W_ih, W_hh, b_ih, b_hh,
                                        W_lin, b_lin, W_fin, b_fin, hs, out, T);
    postproc_kernel<<<T/128, 128, 0, stream>>>(hs, W_lin, b_lin, W_fin, b_fin, out, T);
  } else {
    lstm_scan<2><<<1, 256, 0, stream>>>(nullptr, x, W_ih, W_hh, b_ih, b_hh,
                                        W_lin, b_lin, W_fin, b_fin, nullptr, out, T);
  }
}

// Round 4
// 47427.148 us; speedup vs baseline: 1.2331x; 1.0823x over previous
//
#include <hip/hip_runtime.h>
#include <hip/hip_bf16.h>

__device__ __forceinline__ float fast_exp2(float x){
#if __has_builtin(__builtin_amdgcn_exp2f)
  return __builtin_amdgcn_exp2f(x);
#else
  return exp2f(x);
#endif
}
__device__ __forceinline__ float fast_rcp(float x){
#if __has_builtin(__builtin_amdgcn_rcpf)
  return __builtin_amdgcn_rcpf(x);
#else
  return 1.0f/x;
#endif
}

// quad_perm DPP: 0xB1 = [1,0,3,2] (xor1), 0x4E = [2,3,0,1] (xor2), 0x1B = xor3
template<int CTRL>
__device__ __forceinline__ float qperm(float v){
  return __int_as_float(__builtin_amdgcn_update_dpp(0, __float_as_int(v), CTRL, 0xF, 0xF, true));
}
// sum over the 4 lanes of a quad, result in every lane (verified primitive)
__device__ __forceinline__ float quad_sum(float v){
  v += qperm<0xB1>(v);
  v += qperm<0x4E>(v);
  return v;
}

// LDS-only barrier: do NOT drain vmcnt (prefetch loads / hs stores stay in flight).
#define LDS_BARRIER() __asm__ __volatile__("s_waitcnt lgkmcnt(0)\n\ts_barrier" ::: "memory")

#define LOG2E 1.442695040888963f

// xproj lane->row mapping: tid=(w,l): row = (l&3)*64 + w*16 + (l>>2).
// => float4 at unit u = w*16+(l>>2) holds (zi,zf,zg,zo).
__global__ __launch_bounds__(256) void xproj_kernel(
    const float* __restrict__ x, const float* __restrict__ W_ih,
    const float* __restrict__ b_ih, const float* __restrict__ b_hh,
    float* __restrict__ xp, int T)
{
  const int tid = threadIdx.x;
  const int w = tid >> 6, l = tid & 63;
  const int row = (l & 3) * 64 + w * 16 + (l >> 2);
  float wv[64];
  {
    const float4* wr = (const float4*)(W_ih + (size_t)row*64);
    #pragma unroll
    for (int k=0;k<16;++k){ float4 q = wr[k]; wv[4*k]=q.x; wv[4*k+1]=q.y; wv[4*k+2]=q.z; wv[4*k+3]=q.w; }
  }
  const float bias = b_ih[row] + b_hh[row];
  __shared__ alignas(16) float xs[8][64];
  const int t0 = blockIdx.x * 128;
  for (int tt=0; tt<128; tt+=8){
    __syncthreads();
    xs[tid>>6][tid&63] = x[(size_t)(t0+tt)*64 + tid];
    const int f2i = tid + 256;
    xs[f2i>>6][f2i&63] = x[(size_t)(t0+tt)*64 + f2i];
    __syncthreads();
    #pragma unroll
    for (int j=0;j<8;++j){
      const float4* xr = (const float4*)xs[j];
      float a0=0,a1=0,a2=0,a3=0;
      #pragma unroll
      for (int k=0;k<16;++k){
        float4 q = xr[k];
        a0 = fmaf(wv[4*k+0], q.x, a0);
        a1 = fmaf(wv[4*k+1], q.y, a1);
        a2 = fmaf(wv[4*k+2], q.z, a2);
        a3 = fmaf(wv[4*k+3], q.w, a3);
      }
      xp[(size_t)(t0+tt+j)*256 + tid] = bias + ((a0+a1)+(a2+a3));
    }
  }
}

// ---- MODE 0 fast path: quad-local k-split-4 scan ---------------------------
// 256 threads. lane (w,l): slice s=l&3, unit u=w*16+(l>>2).
// Lane computes partials for ALL 4 gates of unit u over k in [16s,16s+16):
// 8 ds_read_b64 of h per step (4x less LDS->RF than one-row-per-lane).
// Cross-slice reduce = intra-quad DPP sum. All-verified primitives only.
__global__ __launch_bounds__(256,1) void lstm_scan_q4(
    const float* __restrict__ xp, const float* __restrict__ W_hh,
    float* __restrict__ hs, int T)
{
  const int tid = threadIdx.x;
  const int w = tid >> 6, l = tid & 63;
  const int s = l & 3;
  const int u = w * 16 + (l >> 2);

  // weights: wg[g][m] = W_hh[g*64+u][16s+m], m in [0,16)
  float wg[4][16];
  #pragma unroll
  for (int g=0; g<4; ++g){
    const float4* wr = (const float4*)(W_hh + (size_t)(g*64 + u)*64 + s*16);
    #pragma unroll
    for (int q=0; q<4; ++q){
      float4 t = wr[q];
      wg[g][4*q+0]=t.x; wg[g][4*q+1]=t.y; wg[g][4*q+2]=t.z; wg[g][4*q+3]=t.w;
    }
  }

  __shared__ alignas(16) float hb[2][64];
  if (tid < 64){ hb[0][tid] = 0.f; hb[1][tid] = 0.f; }

  float c = 0.f;
  const float4* xpu = ((const float4*)xp) + u;   // quad lanes share address
  float4 cur[8], nxt[8];
  #pragma unroll
  for (int j=0;j<8;++j) cur[j] = xpu[(size_t)j*64];
  float* hsu = hs + u;

  __syncthreads();

  for (int tb = 0; tb < T; tb += 8){
    if (tb + 8 < T){
      #pragma unroll
      for (int j=0;j<8;++j) nxt[j] = xpu[(size_t)(tb+8+j)*64];
    }
    #pragma unroll
    for (int j=0;j<8;++j){
      const int t = tb + j;
      const float2* hp = (const float2*)(&hb[t&1][s*16]);
      float aI0=0,aI1=0, aF0=0,aF1=0, aG0=0,aG1=0, aO0=0,aO1=0;
      #pragma unroll
      for (int m=0;m<8;++m){
        float2 hh = hp[m];
        aI0 = fmaf(wg[0][2*m  ], hh.x, aI0);
        aI1 = fmaf(wg[0][2*m+1], hh.y, aI1);
        aF0 = fmaf(wg[1][2*m  ], hh.x, aF0);
        aF1 = fmaf(wg[1][2*m+1], hh.y, aF1);
        aG0 = fmaf(wg[2][2*m  ], hh.x, aG0);
        aG1 = fmaf(wg[2][2*m+1], hh.y, aG1);
        aO0 = fmaf(wg[3][2*m  ], hh.x, aO0);
        aO1 = fmaf(wg[3][2*m+1], hh.y, aO1);
      }
      // reduce across the 4 slices of this quad (DPP, verified)
      const float zi = quad_sum(aI0 + aI1) + cur[j].x;
      const float zf = quad_sum(aF0 + aF1) + cur[j].y;
      const float zg = quad_sum(aG0 + aG1) + cur[j].z;
      const float zo = quad_sum(aO0 + aO1) + cur[j].w;
      const float i_ = fast_rcp(1.f + fast_exp2(-LOG2E * zi));
      const float f_ = fast_rcp(1.f + fast_exp2(-LOG2E * zf));
      const float o_ = fast_rcp(1.f + fast_exp2(-LOG2E * zo));
      const float g_ = fmaf(fast_rcp(1.f + fast_exp2(-2.f*LOG2E * zg)), 2.f, -1.f);
      c = fmaf(f_, c, i_ * g_);
      const float tc = fmaf(fast_rcp(1.f + fast_exp2(-2.f*LOG2E * c)), 2.f, -1.f);
      const float h = o_ * tc;
      if (s == 0){
        hb[(t&1)^1][u] = h;
        hsu[(size_t)t*64] = h;
      }
      LDS_BARRIER();
    }
    #pragma unroll
    for (int j=0;j<8;++j) cur[j] = nxt[j];
  }
}

// ---- fallback scan (MODES 1,2) — round-2-verified structure ----------------
template<int MODE>
__global__ __launch_bounds__(256,1) void lstm_scan(
    const float* __restrict__ xp, const float* __restrict__ x,
    const float* __restrict__ W_ih, const float* __restrict__ W_hh,
    const float* __restrict__ b_ih, const float* __restrict__ b_hh,
    const float* __restrict__ W_lin, const float* __restrict__ b_lin,
    const float* __restrict__ W_fin, const float* __restrict__ b_fin,
    float* __restrict__ hs, float* __restrict__ out, int T)
{
  const int tid = threadIdx.x;
  const int w = tid >> 6, l = tid & 63;
  const int gate = l & 3;
  const int u64i = w * 16 + (l >> 2);
  const int row = gate * 64 + u64i;

  float wv[64];
  { const float4* wr = (const float4*)(W_hh + (size_t)row*64);
    #pragma unroll
    for (int k=0;k<16;++k){ float4 q=wr[k]; wv[4*k]=q.x; wv[4*k+1]=q.y; wv[4*k+2]=q.z; wv[4*k+3]=q.w; } }

  const bool isg = (gate == 2);
  const float kscale = isg ? (-2.f*LOG2E) : (-LOG2E);
  const float kmul = isg ? 2.f : 1.f;
  const float kadd = isg ? -1.f : 0.f;
  float c = 0.f;

  __shared__ alignas(16) float hbufs[2][64];
  if (tid < 64){ hbufs[0][tid] = 0.f; hbufs[1][tid] = 0.f; }

  float wih[64]; float bias = 0.f;
  __shared__ alignas(16) float xlds[2][512];
  float px0=0.f, px1=0.f;
  const size_t N = (size_t)T * 64;

  {
    const float4* wr = (const float4*)(W_ih + (size_t)row*64);
    #pragma unroll
    for (int k=0;k<16;++k){ float4 q=wr[k]; wih[4*k]=q.x; wih[4*k+1]=q.y; wih[4*k+2]=q.z; wih[4*k+3]=q.w; }
    bias = b_ih[row] + b_hh[row];
    px0 = x[tid]; px1 = x[(size_t)tid + 256];
    xlds[0][tid] = px0; xlds[0][tid+256] = px1;
    size_t i0 = (size_t)512 + tid, i1 = (size_t)512 + tid + 256;
    px0 = x[i0 < N ? i0 : (N-1)];
    px1 = x[i1 < N ? i1 : (N-1)];
  }

  float wlin[64], blin_l=0.f, wfin_l=0.f, bfin=0.f;
  if (MODE == 2){
    const float4* wr = (const float4*)(W_lin + (size_t)l*64);
    #pragma unroll
    for (int k=0;k<16;++k){ float4 q=wr[k]; wlin[4*k]=q.x; wlin[4*k+1]=q.y; wlin[4*k+2]=q.z; wlin[4*k+3]=q.w; }
    blin_l = b_lin[l]; wfin_l = W_fin[l]; bfin = b_fin[0];
  }

  __syncthreads();

  for (int tb = 0; tb < T; tb += 8){
    {
      const int gi = tb >> 3;
      float* xd = xlds[(gi+1)&1];
      xd[tid] = px0; xd[tid+256] = px1;
      const size_t base = (size_t)(gi+2) * 512;
      size_t i0 = base + tid, i1 = base + tid + 256;
      px0 = x[i0 < N ? i0 : (N-1)];
      px1 = x[i1 < N ? i1 : (N-1)];
    }
    #pragma unroll
    for (int j=0;j<8;++j){
      const int t = tb + j;
      const float4* hbp = (const float4*)hbufs[t&1];
      float a0=0,a1=0,a2=0,a3=0;
      float m0=0,m1=0,m2=0,m3=0;
      #pragma unroll
      for (int k=0;k<16;++k){
        float4 hk = hbp[k];
        a0 = fmaf(wv[4*k+0], hk.x, a0);
        a1 = fmaf(wv[4*k+1], hk.y, a1);
        a2 = fmaf(wv[4*k+2], hk.z, a2);
        a3 = fmaf(wv[4*k+3], hk.w, a3);
        if (MODE == 2){
          m0 = fmaf(wlin[4*k+0], fmaxf(hk.x,0.f), m0);
          m1 = fmaf(wlin[4*k+1], fmaxf(hk.y,0.f), m1);
          m2 = fmaf(wlin[4*k+2], fmaxf(hk.z,0.f), m2);
          m3 = fmaf(wlin[4*k+3], fmaxf(hk.w,0.f), m3);
        }
      }
      float z = (a0+a1)+(a2+a3);
      {
        const float4* xr = (const float4*)&xlds[(tb>>3)&1][j*64];
        float b0=0,b1=0,b2=0,b3=0;
        #pragma unroll
        for (int k=0;k<16;++k){
          float4 q = xr[k];
          b0 = fmaf(wih[4*k+0], q.x, b0);
          b1 = fmaf(wih[4*k+1], q.y, b1);
          b2 = fmaf(wih[4*k+2], q.z, b2);
          b3 = fmaf(wih[4*k+3], q.w, b3);
        }
        z += bias + ((b0+b1)+(b2+b3));
      }
      if (MODE == 2){
        float mid = fmaxf(blin_l + ((m0+m1)+(m2+m3)), 0.f);
        float po = wfin_l * mid;
        if (w == 0){
          po += __shfl_xor(po,1); po += __shfl_xor(po,2); po += __shfl_xor(po,4);
          po += __shfl_xor(po,8); po += __shfl_xor(po,16); po += __shfl_xor(po,32);
          if (l == 0 && t > 0) out[t-1] = po + bfin;
        }
      }
      float e = fast_exp2(z * kscale);
      float sgm = fast_rcp(1.f + e);
      float v = fmaf(sgm, kmul, kadd);
      const float q1 = qperm<0xB1>(v);
      const float q2 = qperm<0x4E>(v);
      const float q3 = qperm<0x1B>(v);
      c = fmaf(q1, c, v * q2);
      const float e2 = fast_exp2((-2.f*LOG2E) * c);
      const float tc = fmaf(fast_rcp(1.f + e2), 2.f, -1.f);
      const float h = q3 * tc;
      if ((l & 3) == 0){
        hbufs[(t&1)^1][u64i] = h;
        if (MODE <= 1) hs[(size_t)t*64 + u64i] = h;
      }
      LDS_BARRIER();
    }
  }
  if (MODE == 2){
    const float4* hbp = (const float4*)hbufs[T&1];
    float m0=0,m1=0,m2=0,m3=0;
    #pragma unroll
    for (int k=0;k<16;++k){
      float4 hk = hbp[k];
      m0 = fmaf(wlin[4*k+0], fmaxf(hk.x,0.f), m0);
      m1 = fmaf(wlin[4*k+1], fmaxf(hk.y,0.f), m1);
      m2 = fmaf(wlin[4*k+2], fmaxf(hk.z,0.f), m2);
      m3 = fmaf(wlin[4*k+3], fmaxf(hk.w,0.f), m3);
    }
    float mid = fmaxf(blin_l + ((m0+m1)+(m2+m3)), 0.f);
    float po = wfin_l * mid;
    if (w == 0){
      po += __shfl_xor(po,1); po += __shfl_xor(po,2); po += __shfl_xor(po,4);
      po += __shfl_xor(po,8); po += __shfl_xor(po,16); po += __shfl_xor(po,32);
      if (l == 0) out[T-1] = po + bfin;
    }
  }
}

__global__ __launch_bounds__(128) void postproc_kernel(
    const float* __restrict__ hs, const float* __restrict__ W_lin,
    const float* __restrict__ b_lin, const float* __restrict__ W_fin,
    const float* __restrict__ b_fin, float* __restrict__ out, int T)
{
  __shared__ alignas(16) float wl[4096];
  __shared__ float ht[128][65];
  __shared__ float sb[64], sw[64];
  const int tid = threadIdx.x;
  #pragma unroll
  for (int i=0;i<32;++i){ int f = tid + i*128; wl[f] = W_lin[f]; }
  if (tid < 64){ sb[tid] = b_lin[tid]; sw[tid] = W_fin[tid]; }
  const size_t t0 = (size_t)blockIdx.x * 128;
  #pragma unroll
  for (int i=0;i<64;++i){ int f = tid + i*128; ht[f>>6][f&63] = hs[t0*64 + f]; }
  __syncthreads();
  float rh[64];
  #pragma unroll
  for (int k=0;k<64;++k) rh[k] = fmaxf(ht[tid][k], 0.f);
  float acc = b_fin[0];
  for (int j=0;j<64;++j){
    const float4* wr = (const float4*)(wl + j*64);
    float m0=sb[j],m1=0,m2=0,m3=0;
    #pragma unroll
    for (int k=0;k<16;++k){
      float4 q = wr[k];
      m0 = fmaf(q.x, rh[4*k+0], m0);
      m1 = fmaf(q.y, rh[4*k+1], m1);
      m2 = fmaf(q.z, rh[4*k+2], m2);
      m3 = fmaf(q.w, rh[4*k+3], m3);
    }
    acc = fmaf(sw[j], fmaxf((m0+m1)+(m2+m3), 0.f), acc);
  }
  out[t0 + tid] = acc;
}

extern "C" void kernel_launch(void* const* d_in, const int* in_sizes, int n_in,
                              void* d_out, int out_size, void* d_ws, size_t ws_size,
                              hipStream_t stream)
{
  const float* x    = (const float*)d_in[0];
  const float* W_ih = (const float*)d_in[1];
  const float* W_hh = (const float*)d_in[2];
  const float* b_ih = (const float*)d_in[3];
  const float* b_hh = (const float*)d_in[4];
  const float* W_lin= (const float*)d_in[5];
  const float* b_lin= (const float*)d_in[6];
  const float* W_fin= (const float*)d_in[7];
  const float* b_fin= (const float*)d_in[8];
  float* out = (float*)d_out;
  const int T = in_sizes[0] / 64;
  const size_t xp_bytes = (size_t)T * 256 * sizeof(float);
  const size_t hs_bytes = (size_t)T * 64 * sizeof(float);

  if (ws_size >= xp_bytes + hs_bytes){
    float* xp = (float*)d_ws;
    float* hs = (float*)((char*)d_ws + xp_bytes);
    xproj_kernel<<<T/128, 256, 0, stream>>>(x, W_ih, b_ih, b_hh, xp, T);
    lstm_scan_q4<<<1, 256, 0, stream>>>(xp, W_hh, hs, T);
    postproc_kernel<<<T/128, 128, 0, stream>>>(hs, W_lin, b_lin, W_fin, b_fin, out, T);
  } else if (ws_size >= hs_bytes){
    float* hs = (float*)d_ws;
    lstm_scan<1><<<1, 256, 0, stream>>>(nullptr, x, W_ih, W_hh, b_ih, b_hh,
                                        W_lin, b_lin, W_fin, b_fin, hs, out, T);
    postproc_kernel<<<T/128, 128, 0, stream>>>(hs, W_lin, b_lin, W_fin, b_fin, out, T);
  } else {
    lstm_scan<2><<<1, 256, 0, stream>>>(nullptr, x, W_ih, W_hh, b_ih, b_hh,
                                        W_lin, b_lin, W_fin, b_fin, nullptr, out, T);
  }
}